// Round 1
// 1272.245 us; speedup vs baseline: 1.0340x; 1.0340x over previous
//
#include <hip/hip_runtime.h>
#include <math.h>

// Problem constants (from reference)
constexpr int kB    = 1024;     // batch
constexpr int kP    = 10;       // positives per row
constexpr int kNeg  = 990;      // negatives per row
constexpr int kCols = 1000;     // P + NEG
constexpr int kNI1  = 20001;    // NI + 1 (stats row stride)
constexpr long long kStatsN = 200030001LL; // (NU+1)*(NI+1)
constexpr float kMom = 0.9f;
constexpr float kEps = 1e-10f;

// Workspace layout (floats unless noted)
// [0..1023]      T0[b]   = sum_j exp(neg)
// [1024..2047]   T1[b]   = sum_j neg*exp(neg)
// [2048..3071]   mm[b]   = maxneg - minpos
// [3072..4095]   fair[b] = (diff*sqrt(FW))^2
// [4097] fair_sum   [4098] main_acc
// [4100..14339]  upd[k]  (k = b*P+p, 10240)
// [14340..24579] key[k]  (int)
constexpr int kOffT0   = 0;
constexpr int kOffT1   = 1024;
constexpr int kOffMM   = 2048;
constexpr int kOffFair = 3072;
constexpr int kOffFS   = 4097;
constexpr int kOffAcc  = 4098;
constexpr int kOffUpd  = 4100;
constexpr int kOffKey  = 14340;

// Shifted-copy geometry: out[1+i] = stats[i].
// Head: stats[0..2] scalar. Body: chunk c covers stats[3+4c..6+4c] ->
// aligned float4 store at out+4+4c. Tail: 2 scalar elements.
constexpr long long kChunks = (kStatsN - 3) / 4;      // 50,007,499 (rem 2)
constexpr int kChunksPerBlock = 1024;                 // 256 thr x 4
constexpr int kCopyBlocks =
    (int)((kChunks + kChunksPerBlock - 1) / kChunksPerBlock);  // 48,836

__device__ inline float wave_sum(float v) {
    for (int o = 32; o > 0; o >>= 1) v += __shfl_xor(v, o, 64);
    return v;
}
__device__ inline float wave_max(float v) {
    for (int o = 32; o > 0; o >>= 1) v = fmaxf(v, __shfl_xor(v, o, 64));
    return v;
}
__device__ inline float wave_min(float v) {
    for (int o = 32; o > 0; o >>= 1) v = fminf(v, __shfl_xor(v, o, 64));
    return v;
}

// K1: fused {row-stats for blocks [0,1024)} + {vectorized shifted copy for the rest}.
// Row-stats blocks are dispatched first and finish within the copy's shadow.
__global__ __launch_bounds__(256) void k_main(const float* __restrict__ pred,
                                              const float* __restrict__ aidx,
                                              const float* __restrict__ bidx,
                                              const float* __restrict__ stats,
                                              float* __restrict__ out,
                                              float* __restrict__ ws) {
    const int blk = blockIdx.x;
    const int t = threadIdx.x;

    if (blk < kB) {
        // housekeeping: scalar head/tail of the shifted copy + zero the loss acc
        if (blk == 0) {
            if (t == 64) {
                out[1] = stats[0]; out[2] = stats[1]; out[3] = stats[2];
            } else if (t == 65) {
                out[kStatsN - 1] = stats[kStatsN - 2];
                out[kStatsN]     = stats[kStatsN - 1];
            } else if (t == 66) {
                ws[kOffAcc] = 0.f;
            }
        }
        const int b = blk;
        const float* row = pred + (long long)b * kCols;
        const float* ar  = aidx + (long long)b * kCols;
        const float* br  = bidx + (long long)b * kCols;

        float sumexp = 0.f, sa = 0.f, sb = 0.f, T0 = 0.f, T1 = 0.f;
        float posmin = INFINITY, negmax = -INFINITY;
#pragma unroll
        for (int q = 0; q < 4; ++q) {
            int i = t + q * 256;
            if (i < kCols) {
                float x  = row[i];
                float ex = expf(x);
                sumexp += ex;
                sa += ar[i] * ex;
                sb += br[i] * ex;
                if (i < kP) {
                    posmin = fminf(posmin, x);
                } else {
                    negmax = fmaxf(negmax, x);
                    T0 += ex;
                    T1 += x * ex;
                }
            }
        }
        sumexp = wave_sum(sumexp);
        sa     = wave_sum(sa);
        sb     = wave_sum(sb);
        T0     = wave_sum(T0);
        T1     = wave_sum(T1);
        posmin = wave_min(posmin);
        negmax = wave_max(negmax);

        __shared__ float red[7][4];
        const int w = t >> 6, lane = t & 63;
        if (lane == 0) {
            red[0][w] = sumexp; red[1][w] = sa; red[2][w] = sb;
            red[3][w] = T0;     red[4][w] = T1;
            red[5][w] = posmin; red[6][w] = negmax;
        }
        __syncthreads();
        if (t == 0) {
            float se = 0.f, a = 0.f, bb = 0.f, t0 = 0.f, t1 = 0.f;
            float pm = INFINITY, nm = -INFINITY;
#pragma unroll
            for (int i = 0; i < 4; ++i) {
                se += red[0][i]; a += red[1][i]; bb += red[2][i];
                t0 += red[3][i]; t1 += red[4][i];
                pm = fminf(pm, red[5][i]); nm = fmaxf(nm, red[6][i]);
            }
            float diff = (bb - a) / se;
            float fw   = sqrtf(100000.0f);
            float d2   = diff * fw;
            ws[kOffT0 + b]   = t0;
            ws[kOffT1 + b]   = t1;
            ws[kOffMM + b]   = nm - pm;
            ws[kOffFair + b] = d2 * d2;
        }
        return;
    }

    // vectorized shifted copy: both loads and stores are aligned float4.
    const long long c0 = (long long)(blk - kB) * kChunksPerBlock + t;
    const float4* __restrict__ s4 = (const float4*)stats;
#pragma unroll
    for (int q = 0; q < 4; ++q) {
        long long c = c0 + (long long)q * 256;
        if (c < kChunks) {
            float4 A  = s4[c];       // stats[4c..4c+3]
            float4 Bv = s4[c + 1];   // stats[4c+4..4c+7]  (L1/MSHR-merged)
            float4 r;
            r.x = A.w; r.y = Bv.x; r.z = Bv.y; r.w = Bv.z;  // stats[3+4c..6+4c]
            *reinterpret_cast<float4*>(out + 4 + 4 * c) = r; // out 16B-aligned
        }
    }
}

// K2: per-(b,p) updated stats + main-loss partials. Each block redundantly
// reduces the global margin max M (4 KB from L2); block 0 also sums fairness.
__global__ __launch_bounds__(256) void k_perk(const float* __restrict__ pred,
                                              const float* __restrict__ stats,
                                              const int* __restrict__ uid,
                                              const int* __restrict__ iid,
                                              float* __restrict__ ws) {
    const int t = threadIdx.x;
    const int w = t >> 6, lane = t & 63;

    float mm = -INFINITY;
#pragma unroll
    for (int q = 0; q < 4; ++q) mm = fmaxf(mm, ws[kOffMM + t + q * 256]);
    mm = wave_max(mm);

    float fs = 0.f;
    if (blockIdx.x == 0) {
#pragma unroll
        for (int q = 0; q < 4; ++q) fs += ws[kOffFair + t + q * 256];
        fs = wave_sum(fs);
    }

    __shared__ float rm[4], rf[4];
    __shared__ float Msh;
    if (lane == 0) { rm[w] = mm; if (blockIdx.x == 0) rf[w] = fs; }
    __syncthreads();
    if (t == 0) {
        Msh = fmaxf(fmaxf(rm[0], rm[1]), fmaxf(rm[2], rm[3]));
        if (blockIdx.x == 0) ws[kOffFS] = rf[0] + rf[1] + rf[2] + rf[3];
    }
    __syncthreads();
    const float M = Msh;

    const int k = blockIdx.x * 256 + t;   // exactly 10240 threads
    const int b = k / kP;
    const int p = k - b * kP;
    float pos = pred[(long long)b * kCols + p];
    float T0  = ws[kOffT0 + b];
    float T1  = ws[kOffT1 + b];
    float s   = expf(-pos - M);
    float mean_e = s * T0 * (1.0f / kNeg);
    int u  = uid[b];
    int it = iid[k];
    int key = u * kNI1 + it;
    float cur = stats[(long long)key];
    float upd = (1.0f - kMom) * cur + kMom * mean_e;
    ws[kOffUpd + k] = upd;
    ((int*)ws)[kOffKey + k] = key;
    float c = s * (T1 - pos * T0) / (upd + kEps);

    c = wave_sum(c);
    __shared__ float racc[4];
    if (lane == 0) racc[w] = c;
    __syncthreads();
    if (t == 0) {
        atomicAdd(&ws[kOffAcc], racc[0] + racc[1] + racc[2] + racc[3]);
    }
}

// K3: scatter updated values (last-occurrence-wins) + write loss
__global__ __launch_bounds__(256) void k_scatter(float* __restrict__ out,
                                                 const float* __restrict__ ws) {
    const int k = blockIdx.x;
    const int* keys = (const int*)ws + kOffKey;
    __shared__ int dupflag;
    if (threadIdx.x == 0) dupflag = 0;
    __syncthreads();
    const int key = keys[k];
    for (int j = k + 1 + threadIdx.x; j < kB * kP; j += 256) {
        if (keys[j] == key) dupflag = 1;   // benign race, same value
    }
    __syncthreads();
    if (threadIdx.x == 0 && !dupflag) {
        out[1 + (long long)key] = ws[kOffUpd + k];
    }
    if (blockIdx.x == 0 && threadIdx.x == 255) {
        out[0] = ws[kOffAcc] * (1.0f / kB) + ws[kOffFS] * (1.0f / kB);
    }
}

extern "C" void kernel_launch(void* const* d_in, const int* in_sizes, int n_in,
                              void* d_out, int out_size, void* d_ws, size_t ws_size,
                              hipStream_t stream) {
    const float* pred  = (const float*)d_in[0];
    const float* stats = (const float*)d_in[1];
    const int*   uid   = (const int*)d_in[2];
    const int*   iid   = (const int*)d_in[3];
    const float* aidx  = (const float*)d_in[4];
    const float* bidx  = (const float*)d_in[5];
    float* out = (float*)d_out;
    float* ws  = (float*)d_ws;

    k_main<<<kB + kCopyBlocks, 256, 0, stream>>>(pred, aidx, bidx, stats, out, ws);
    k_perk<<<(kB * kP) / 256, 256, 0, stream>>>(pred, stats, uid, iid, ws);
    k_scatter<<<kB * kP, 256, 0, stream>>>(out, ws);
}